// Round 1
// baseline (222.325 us; speedup 1.0000x reference)
//
#include <hip/hip_runtime.h>

// BilinearInterpolation (spatial transformer sampling)
// image: [32, 512, 512, 4] f32 (NHWC, C=4 -> one pixel == one native float4)
// affine: [32, 6] f32
// out:   [32, 512, 512, 4] f32
//
// v2: 2 output pixels per thread (rows i and i+4 of a 64x8 block tile).
// Rationale: kernel is memory-bound (floor ~43us: 134MB read + 134MB NT
// write @6.3TB/s); a pixel is exactly one dwordx4 so load widening is
// impossible — the remaining lever is per-thread MLP (8 gathers in flight
// instead of 4) and halving per-output setup/wave count.

#define IMG_H 512
#define IMG_W 512
#define OUT_H 512
#define OUT_W 512
#define NBATCH 32
#define TILE_X 64
#define TILE_Y 4                         // thread rows per block
#define ROWS_PER_THREAD 2
#define BLOCK_ROWS (TILE_Y * ROWS_PER_THREAD)   // 8 output rows per block

// native clang vector — required by __builtin_nontemporal_store
typedef float fx4 __attribute__((ext_vector_type(4)));

__global__ __launch_bounds__(256) void bilerp_kernel(
    const float* __restrict__ image,
    const float* __restrict__ affine,
    float* __restrict__ out)
{
    const int tx = threadIdx.x & 63;        // 0..63 (one wave spans a 64-wide row)
    const int ty = threadIdx.x >> 6;        // 0..3
    const int j  = blockIdx.x * TILE_X + tx;     // output col
    const int i0 = blockIdx.y * BLOCK_ROWS + ty; // output row (first)
    const int i1 = i0 + TILE_Y;                  // output row (second)
    const int b  = blockIdx.z;

    // normalized grid coords, linspace(-1, 1, 512) -> step = 2/511
    const float step = 2.0f / 511.0f;
    const float xn  = -1.0f + step * (float)j;
    const float yn0 = -1.0f + step * (float)i0;
    const float yn1 = -1.0f + step * (float)i1;

    // per-batch affine (6 floats) — uniform across block, scalar-cached
    const float* t = affine + b * 6;
    const float t0 = t[0], t1 = t[1], t2 = t[2];
    const float t3 = t[3], t4 = t[4], t5 = t[5];

    // ---- row 0: coords / corners / weights ----
    float x0 = t0 * xn + t1 * yn0 + t2;
    float y0 = t3 * xn + t4 * yn0 + t5;
    x0 = 0.5f * (x0 + 1.0f) * (float)IMG_W;
    y0 = 0.5f * (y0 + 1.0f) * (float)IMG_H;

    int xm0 = (int)x0;                      // trunc toward zero (matches astype)
    int ym0 = (int)y0;
    int xM0 = xm0 + 1;
    int yM0 = ym0 + 1;
    xm0 = min(max(xm0, 0), IMG_W - 1);
    xM0 = min(max(xM0, 0), IMG_W - 1);
    ym0 = min(max(ym0, 0), IMG_H - 1);
    yM0 = min(max(yM0, 0), IMG_H - 1);

    const float xmf0 = (float)xm0, xMf0 = (float)xM0;
    const float ymf0 = (float)ym0, yMf0 = (float)yM0;
    const float aA0 = (xMf0 - x0) * (yMf0 - y0);
    const float aB0 = (xMf0 - x0) * (y0 - ymf0);
    const float aC0 = (x0 - xmf0) * (yMf0 - y0);
    const float aD0 = (x0 - xmf0) * (y0 - ymf0);

    // ---- row 1: coords / corners / weights ----
    float x1 = t0 * xn + t1 * yn1 + t2;
    float y1 = t3 * xn + t4 * yn1 + t5;
    x1 = 0.5f * (x1 + 1.0f) * (float)IMG_W;
    y1 = 0.5f * (y1 + 1.0f) * (float)IMG_H;

    int xm1 = (int)x1;
    int ym1 = (int)y1;
    int xM1 = xm1 + 1;
    int yM1 = ym1 + 1;
    xm1 = min(max(xm1, 0), IMG_W - 1);
    xM1 = min(max(xM1, 0), IMG_W - 1);
    ym1 = min(max(ym1, 0), IMG_H - 1);
    yM1 = min(max(yM1, 0), IMG_H - 1);

    const float xmf1 = (float)xm1, xMf1 = (float)xM1;
    const float ymf1 = (float)ym1, yMf1 = (float)yM1;
    const float aA1 = (xMf1 - x1) * (yMf1 - y1);
    const float aB1 = (xMf1 - x1) * (y1 - ymf1);
    const float aC1 = (x1 - xmf1) * (yMf1 - y1);
    const float aD1 = (x1 - xmf1) * (y1 - ymf1);

    // ---- issue all 8 gathers before any blend (max MLP) ----
    const fx4* __restrict__ img = (const fx4*)image + (size_t)b * (IMG_H * IMG_W);
    const int rm0 = ym0 * IMG_W, rM0 = yM0 * IMG_W;
    const int rm1 = ym1 * IMG_W, rM1 = yM1 * IMG_W;

    const fx4 pA0 = img[rm0 + xm0];
    const fx4 pC0 = img[rm0 + xM0];
    const fx4 pB0 = img[rM0 + xm0];
    const fx4 pD0 = img[rM0 + xM0];
    const fx4 pA1 = img[rm1 + xm1];
    const fx4 pC1 = img[rm1 + xM1];
    const fx4 pB1 = img[rM1 + xm1];
    const fx4 pD1 = img[rM1 + xM1];

    fx4 o0 = pA0 * aA0 + pB0 * aB0 + pC0 * aC0 + pD0 * aD0;
    fx4 o1 = pA1 * aA1 + pB1 * aB1 + pC1 * aC1 + pD1 * aD1;

    // output is never re-read: non-temporal stores keep L2 for image lines
    fx4* op = (fx4*)out + (size_t)b * (OUT_H * OUT_W);
    __builtin_nontemporal_store(o0, op + (size_t)i0 * OUT_W + j);
    __builtin_nontemporal_store(o1, op + (size_t)i1 * OUT_W + j);
}

extern "C" void kernel_launch(void* const* d_in, const int* in_sizes, int n_in,
                              void* d_out, int out_size, void* d_ws, size_t ws_size,
                              hipStream_t stream)
{
    const float* image  = (const float*)d_in[0];   // 32*512*512*4
    const float* affine = (const float*)d_in[1];   // 32*6
    float* out = (float*)d_out;

    dim3 block(256);
    dim3 grid(OUT_W / TILE_X, OUT_H / BLOCK_ROWS, NBATCH);
    bilerp_kernel<<<grid, block, 0, stream>>>(image, affine, out);
}